// Round 1
// baseline (2295.823 us; speedup 1.0000x reference)
//
#include <hip/hip_runtime.h>
#include <math.h>

// EGCL_Multi: N=512 nodes, NH=8 heads, HD=128, M=256 mlp width.
// Pipeline: per-node P/Q precompute -> fused per-edge MLP kernel -> finalize.
#define N_NODES 512
#define NH 8
#define HD 128
#define F_DIM 192   // HD + NH*NH
#define M 256
#define JT 8        // edges per block (register blocking over edges)

__device__ __forceinline__ float silu_f(float v) { return v / (1.f + __expf(-v)); }

// ---------------------------------------------------------------------------
// Kernel 1: per-node hc = [h, sqh]; P[i] = hc[i] @ We0[8:200,:],
//           Q[i] = hc[i] @ We0[200:392,:]  (layer-0 algebraic split)
// ---------------------------------------------------------------------------
__global__ __launch_bounds__(256) void k_pq(
    const float* __restrict__ x, const float* __restrict__ h,
    const float* __restrict__ We0,
    float* __restrict__ P, float* __restrict__ Q)
{
  const int i = blockIdx.x, t = threadIdx.x;
  __shared__ float s_x[24];
  __shared__ float s_hc[F_DIM];
  if (t < 24) s_x[t] = x[i * 24 + t];
  __syncthreads();
  if (t < HD) {
    s_hc[t] = h[i * HD + t];
  } else if (t < F_DIM) {
    const int p = t - HD, a = p >> 3, b = p & 7;
    float s = 0.f;
#pragma unroll
    for (int d = 0; d < 3; ++d) {
      const float dx = s_x[a * 3 + d] - s_x[b * 3 + d];
      s = fmaf(dx, dx, s);
    }
    s_hc[t] = s;
  }
  __syncthreads();
  float p = 0.f, q = 0.f;
  for (int k = 0; k < F_DIM; ++k) {
    const float hv = s_hc[k];
    p = fmaf(hv, We0[(8 + k) * M + t], p);
    q = fmaf(hv, We0[(200 + k) * M + t], q);
  }
  P[i * M + t] = p;
  Q[i * M + t] = q;
}

// ---------------------------------------------------------------------------
// Kernel 2: fused edge pipeline. Block = (node i, tile of JT j's).
// Thread t owns neuron t. Per-edge: L0 (8 MACs + P/Q), L1 -> m, gate e,
// phi_x (3 layers) -> px, accumulate m_i and coordinate shift via atomics.
// ---------------------------------------------------------------------------
__global__ __launch_bounds__(256) void k_edge(
    const float* __restrict__ x,
    const float* __restrict__ P, const float* __restrict__ Q,
    const float* __restrict__ We0, const float* __restrict__ be0,
    const float* __restrict__ We1, const float* __restrict__ be1,
    const float* __restrict__ Winf, const float* __restrict__ binf,
    const float* __restrict__ Wx0, const float* __restrict__ bx0,
    const float* __restrict__ Wx1, const float* __restrict__ bx1,
    const float* __restrict__ Wxo, const float* __restrict__ bxo,
    float* __restrict__ mi_acc, float* __restrict__ shift_acc)
{
  const int i  = blockIdx.x;
  const int j0 = blockIdx.y * JT;
  const int t  = threadIdx.x;

  __shared__ float s_xi[24];
  __shared__ float s_xj[JT][24];
  __shared__ float s_sqn[JT][8];
  __shared__ __align__(16) float s_a[JT][M];
  __shared__ __align__(16) float s_m[JT][M];
  __shared__ float s_red[JT][4];
  __shared__ float s_e[JT];
  __shared__ float s_tmp[JT * 8 * 3];

  if (t < 24) s_xi[t] = x[i * 24 + t];
  if (t < JT * 24) s_xj[t / 24][t % 24] = x[j0 * 24 + t];
  __syncthreads();
  if (t < JT * 8) {
    const int e = t >> 3, hh = t & 7;
    float s = 0.f;
#pragma unroll
    for (int d = 0; d < 3; ++d) {
      const float dx = s_xj[e][hh * 3 + d] - s_xi[hh * 3 + d];
      s = fmaf(dx, dx, s);
    }
    s_sqn[e][hh] = s;
  }

  // per-thread persistent values (loaded while sqn is computed)
  const float qreg  = Q[i * M + t] + be0[t];
  float w0k[8];
#pragma unroll
  for (int k = 0; k < 8; ++k) w0k[k] = We0[k * M + t];
  const float winft = Winf[t];
  __syncthreads();

  // ----- layer 0: acc = be0 + Q[i] + P[j] + sqn . We0[0:8] -----
#pragma unroll
  for (int e = 0; e < JT; ++e) {
    float acc = qreg + P[(j0 + e) * M + t];
#pragma unroll
    for (int k = 0; k < 8; ++k) acc = fmaf(s_sqn[e][k], w0k[k], acc);
    s_a[e][t] = silu_f(acc);
  }
  __syncthreads();

  // ----- layer 1 -> m (silu, zero self-edge) -----
  float mval[JT];
  {
    float acc[JT];
    const float b = be1[t];
#pragma unroll
    for (int e = 0; e < JT; ++e) acc[e] = b;
    for (int k = 0; k < M; k += 4) {
      const float w0 = We1[(k + 0) * M + t];
      const float w1 = We1[(k + 1) * M + t];
      const float w2 = We1[(k + 2) * M + t];
      const float w3 = We1[(k + 3) * M + t];
#pragma unroll
      for (int e = 0; e < JT; ++e) {
        const float4 av = *reinterpret_cast<const float4*>(&s_a[e][k]);
        acc[e] = fmaf(av.x, w0, fmaf(av.y, w1, fmaf(av.z, w2, fmaf(av.w, w3, acc[e]))));
      }
    }
#pragma unroll
    for (int e = 0; e < JT; ++e) {
      float m = silu_f(acc[e]);
      if (j0 + e == i) m = 0.f;   // off-diagonal mask
      mval[e] = m;
      s_m[e][t] = m;
    }
  }

  // ----- gate: e = sigmoid(m . Winf + binf) (block reduction) -----
  {
    float part[JT];
#pragma unroll
    for (int e = 0; e < JT; ++e) part[e] = mval[e] * winft;
#pragma unroll
    for (int off = 32; off > 0; off >>= 1) {
#pragma unroll
      for (int e = 0; e < JT; ++e) part[e] += __shfl_down(part[e], off, 64);
    }
    if ((t & 63) == 0) {
      const int w = t >> 6;
#pragma unroll
      for (int e = 0; e < JT; ++e) s_red[e][w] = part[e];
    }
  }
  __syncthreads();
  if (t < JT) {
    const float tot = s_red[t][0] + s_red[t][1] + s_red[t][2] + s_red[t][3] + binf[0];
    s_e[t] = 1.f / (1.f + __expf(-tot));
  }
  __syncthreads();

  // ----- m_i accumulation (thread t owns channel t of node i) -----
  {
    float macc = 0.f;
#pragma unroll
    for (int e = 0; e < JT; ++e) macc = fmaf(mval[e], s_e[e], macc);
    atomicAdd(&mi_acc[i * M + t], macc);
  }

  // ----- phi_x layer 0: a2 = silu(m @ Wx0 + bx0) -> s_a -----
  {
    float acc[JT];
    const float b = bx0[t];
#pragma unroll
    for (int e = 0; e < JT; ++e) acc[e] = b;
    for (int k = 0; k < M; k += 4) {
      const float w0 = Wx0[(k + 0) * M + t];
      const float w1 = Wx0[(k + 1) * M + t];
      const float w2 = Wx0[(k + 2) * M + t];
      const float w3 = Wx0[(k + 3) * M + t];
#pragma unroll
      for (int e = 0; e < JT; ++e) {
        const float4 av = *reinterpret_cast<const float4*>(&s_m[e][k]);
        acc[e] = fmaf(av.x, w0, fmaf(av.y, w1, fmaf(av.z, w2, fmaf(av.w, w3, acc[e]))));
      }
    }
#pragma unroll
    for (int e = 0; e < JT; ++e) s_a[e][t] = silu_f(acc[e]);
  }
  __syncthreads();

  // ----- phi_x layer 1: a3 = silu(a2 @ Wx1 + bx1) -> s_m (m dead in LDS) -----
  {
    float acc[JT];
    const float b = bx1[t];
#pragma unroll
    for (int e = 0; e < JT; ++e) acc[e] = b;
    for (int k = 0; k < M; k += 4) {
      const float w0 = Wx1[(k + 0) * M + t];
      const float w1 = Wx1[(k + 1) * M + t];
      const float w2 = Wx1[(k + 2) * M + t];
      const float w3 = Wx1[(k + 3) * M + t];
#pragma unroll
      for (int e = 0; e < JT; ++e) {
        const float4 av = *reinterpret_cast<const float4*>(&s_a[e][k]);
        acc[e] = fmaf(av.x, w0, fmaf(av.y, w1, fmaf(av.z, w2, fmaf(av.w, w3, acc[e]))));
      }
    }
#pragma unroll
    for (int e = 0; e < JT; ++e) s_m[e][t] = silu_f(acc[e]);
  }
  __syncthreads();

  // ----- px = a3 @ Wxo + bxo; shift contribution -----
  if (t < JT * 8) {
    const int e = t >> 3, hh = t & 7;
    const int j = j0 + e;
    float c0 = 0.f, c1 = 0.f, c2 = 0.f;
    if (j != i) {
      float px = bxo[hh];
      for (int k = 0; k < M; ++k) px = fmaf(s_m[e][k], Wxo[k * NH + hh], px);
      const float sq  = s_sqn[e][hh];
      const float inv = 1.f / (sqrtf(sq + 1e-8f) + 1.f);  // NORM_CONST = 1
      const float f   = inv * px;
      c0 = (s_xj[e][hh * 3 + 0] - s_xi[hh * 3 + 0]) * f;
      c1 = (s_xj[e][hh * 3 + 1] - s_xi[hh * 3 + 1]) * f;
      c2 = (s_xj[e][hh * 3 + 2] - s_xi[hh * 3 + 2]) * f;
    }
    s_tmp[t * 3 + 0] = c0;
    s_tmp[t * 3 + 1] = c1;
    s_tmp[t * 3 + 2] = c2;
  }
  __syncthreads();
  if (t < 24) {
    const int hh = t / 3, d = t % 3;
    float s = 0.f;
#pragma unroll
    for (int e = 0; e < JT; ++e) s += s_tmp[((e << 3) | hh) * 3 + d];
    atomicAdd(&shift_acc[i * 24 + t], s);
  }
}

// ---------------------------------------------------------------------------
// Kernel 3a: x_new = x + shift / (N-1)
// ---------------------------------------------------------------------------
__global__ void k_xout(const float* __restrict__ x, const float* __restrict__ shift,
                       float* __restrict__ out)
{
  const int idx = blockIdx.x * 256 + threadIdx.x;
  if (idx < N_NODES * NH * 3) out[idx] = x[idx] + shift[idx] * (1.f / 511.f);
}

// ---------------------------------------------------------------------------
// Kernel 3b: h_new = h + phi_h([m_i, h])
// ---------------------------------------------------------------------------
__global__ __launch_bounds__(256) void k_hout(
    const float* __restrict__ h, const float* __restrict__ mi,
    const float* __restrict__ Wh0, const float* __restrict__ bh0,
    const float* __restrict__ Wh1, const float* __restrict__ bh1,
    const float* __restrict__ Who, const float* __restrict__ bho,
    float* __restrict__ out)
{
  const int i = blockIdx.x, t = threadIdx.x;
  __shared__ float s_in[M + HD];  // 384
  __shared__ float s_b[M];
  s_in[t] = mi[i * M + t];
  if (t < HD) s_in[M + t] = h[i * HD + t];
  __syncthreads();
  float acc = bh0[t];
  for (int k = 0; k < M + HD; ++k) acc = fmaf(s_in[k], Wh0[k * M + t], acc);
  s_b[t] = silu_f(acc);
  __syncthreads();
  float acc2 = bh1[t];
  for (int k = 0; k < M; ++k) acc2 = fmaf(s_b[k], Wh1[k * M + t], acc2);
  const float a1v = silu_f(acc2);
  __syncthreads();
  s_in[t] = a1v;
  __syncthreads();
  if (t < HD) {
    float o = bho[t];
    for (int k = 0; k < M; ++k) o = fmaf(s_in[k], Who[k * HD + t], o);
    out[i * HD + t] = h[i * HD + t] + o;
  }
}

// ---------------------------------------------------------------------------
extern "C" void kernel_launch(void* const* d_in, const int* in_sizes, int n_in,
                              void* d_out, int out_size, void* d_ws, size_t ws_size,
                              hipStream_t stream)
{
  const float* x    = (const float*)d_in[0];
  const float* h    = (const float*)d_in[1];
  const float* We0  = (const float*)d_in[2];
  const float* be0  = (const float*)d_in[3];
  const float* We1  = (const float*)d_in[4];
  const float* be1  = (const float*)d_in[5];
  const float* Winf = (const float*)d_in[6];
  const float* binf = (const float*)d_in[7];
  const float* Wx0  = (const float*)d_in[8];
  const float* bx0  = (const float*)d_in[9];
  const float* Wx1  = (const float*)d_in[10];
  const float* bx1  = (const float*)d_in[11];
  const float* Wxo  = (const float*)d_in[12];
  const float* bxo  = (const float*)d_in[13];
  const float* Wh0  = (const float*)d_in[14];
  const float* bh0  = (const float*)d_in[15];
  const float* Wh1  = (const float*)d_in[16];
  const float* bh1  = (const float*)d_in[17];
  const float* Who  = (const float*)d_in[18];
  const float* bho  = (const float*)d_in[19];

  float* out_x = (float*)d_out;                 // [512,8,3] = 12288
  float* out_h = out_x + N_NODES * NH * 3;      // [512,128] = 65536

  // workspace layout (floats): mi[131072] | shift[12288] | P[131072] | Q[131072]
  float* ws    = (float*)d_ws;
  float* mi    = ws;
  float* shift = ws + 131072;
  float* P     = ws + 143360;
  float* Q     = ws + 274432;

  // zero the accumulators (ws is poisoned 0xAA before every call)
  hipMemsetAsync(mi, 0, (131072 + 12288) * sizeof(float), stream);

  k_pq<<<N_NODES, 256, 0, stream>>>(x, h, We0, P, Q);
  k_edge<<<dim3(N_NODES, N_NODES / JT), 256, 0, stream>>>(
      x, P, Q, We0, be0, We1, be1, Winf, binf,
      Wx0, bx0, Wx1, bx1, Wxo, bxo, mi, shift);
  k_xout<<<(N_NODES * NH * 3 + 255) / 256, 256, 0, stream>>>(x, shift, out_x);
  k_hout<<<N_NODES, 256, 0, stream>>>(h, mi, Wh0, bh0, Wh1, bh1, Who, bho, out_h);
}

// Round 2
// 778.801 us; speedup vs baseline: 2.9479x; 2.9479x over previous
//
#include <hip/hip_runtime.h>
#include <math.h>

// EGCL_Multi on MFMA: N=512 nodes, NH=8 heads, HD=128, M=256.
#define N_NODES 512
#define NH 8
#define HD 128
#define M 256
#define PITCH 264        // LDS activation row pitch in bf16 (528B: aligned, 2-way banks)
#define JTILE 128        // edges (j) per block

typedef __bf16 v8bf __attribute__((ext_vector_type(8)));
typedef float f32x4 __attribute__((ext_vector_type(4)));

__device__ __forceinline__ float silu_f(float v) { return v / (1.f + __expf(-v)); }
__device__ __forceinline__ unsigned short f2bf(float f) {
  unsigned u = __float_as_uint(f);
  u += 0x7fffu + ((u >> 16) & 1u);
  return (unsigned short)(u >> 16);
}
__device__ __forceinline__ float bf2f(unsigned short s) {
  return __uint_as_float(((unsigned)s) << 16);
}

// ---------------------------------------------------------------------------
// Weight prep: fp32 [K,N] row-major -> bf16 MFMA-B-fragment order.
// dst[((kt*NT + nt)*64 + lane)*8 + j] = W[kt*32 + (lane>>4)*8 + j][nt*16 + (lane&15)]
// Layers: We1 (256x256) @0, Wx0 @65536, Wx1 @131072, Wxo (256x8 pad->16) @196608.
// ---------------------------------------------------------------------------
__global__ __launch_bounds__(256) void k_prep(
    const float* __restrict__ We1, const float* __restrict__ Wx0,
    const float* __restrict__ Wx1, const float* __restrict__ Wxo,
    unsigned short* __restrict__ wsB)
{
  const int gid = blockIdx.x * 256 + threadIdx.x;
  if (gid >= 200704) return;
  float val;
  if (gid < 196608) {
    const int layer = gid >> 16;           // 0..2
    const int i2 = gid & 65535;
    const int j = i2 & 7, lane = (i2 >> 3) & 63, nt = (i2 >> 9) & 15, kt = i2 >> 13;
    const int k = kt * 32 + (lane >> 4) * 8 + j;
    const int n = nt * 16 + (lane & 15);
    const float* W = (layer == 0) ? We1 : (layer == 1) ? Wx0 : Wx1;
    val = W[k * 256 + n];
  } else {
    const int i2 = gid - 196608;           // [0,4096)
    const int j = i2 & 7, lane = (i2 >> 3) & 63, kt = (i2 >> 9) & 7;
    const int k = kt * 32 + (lane >> 4) * 8 + j;
    const int n = lane & 15;
    val = (n < 8) ? Wxo[k * 8 + n] : 0.f;
  }
  wsB[gid] = f2bf(val);
}

// ---------------------------------------------------------------------------
// Per-node P/Q precompute (layer-0 algebraic split), fp32.
// ---------------------------------------------------------------------------
__global__ __launch_bounds__(256) void k_pq(
    const float* __restrict__ x, const float* __restrict__ h,
    const float* __restrict__ We0,
    float* __restrict__ P, float* __restrict__ Q)
{
  const int i = blockIdx.x, t = threadIdx.x;
  __shared__ float s_x[24];
  __shared__ float s_hc[192];
  if (t < 24) s_x[t] = x[i * 24 + t];
  __syncthreads();
  if (t < HD) {
    s_hc[t] = h[i * HD + t];
  } else if (t < 192) {
    const int p = t - HD, a = p >> 3, b = p & 7;
    float s = 0.f;
#pragma unroll
    for (int d = 0; d < 3; ++d) {
      const float dx = s_x[a * 3 + d] - s_x[b * 3 + d];
      s = fmaf(dx, dx, s);
    }
    s_hc[t] = s;
  }
  __syncthreads();
  float p = 0.f, q = 0.f;
  for (int k = 0; k < 192; ++k) {
    const float hv = s_hc[k];
    p = fmaf(hv, We0[(8 + k) * M + t], p);
    q = fmaf(hv, We0[(200 + k) * M + t], q);
  }
  P[i * M + t] = p;
  Q[i * M + t] = q;
}

// ---------------------------------------------------------------------------
// Fused edge pipeline on MFMA. Block = (i, 128-j tile), 4 waves.
// Wave w owns edge rows [32w, 32w+32) through the whole GEMM chain.
// ---------------------------------------------------------------------------
__global__ __launch_bounds__(256, 2) void k_edge(
    const float* __restrict__ x,
    const float* __restrict__ P, const float* __restrict__ Q,
    const float* __restrict__ We0, const float* __restrict__ be0,
    const float* __restrict__ be1,
    const float* __restrict__ Winf, const float* __restrict__ binf,
    const float* __restrict__ bx0, const float* __restrict__ bx1,
    const float* __restrict__ bxo,
    const unsigned short* __restrict__ wsB,
    float* __restrict__ mi_acc, float* __restrict__ shift_acc)
{
  const int i  = blockIdx.x;
  const int j0 = blockIdx.y * JTILE;
  const int t  = threadIdx.x;
  const int lane = t & 63, wave = t >> 6;
  const int lnib = lane & 15, quad = lane >> 4;
  const int r0 = wave * 32;

  __shared__ __align__(16) unsigned short a_act[JTILE * PITCH];  // 67.6 KB
  __shared__ __align__(16) float s_sqn[JTILE][8];                // 4 KB
  __shared__ float s_e[JTILE];

  // ---- sqn for all 128 rows ----
  for (int idx = t; idx < JTILE * 8; idx += 256) {
    const int r = idx >> 3, hh = idx & 7;
    const int j = j0 + r;
    float s = 0.f;
#pragma unroll
    for (int d = 0; d < 3; ++d) {
      const float dx = x[j * 24 + hh * 3 + d] - x[i * 24 + hh * 3 + d];
      s = fmaf(dx, dx, s);
    }
    s_sqn[r][hh] = s;
  }
  __syncthreads();

  // ---- stage 0: a1 = silu(be0 + Q[i] + P[j] + sqn . We0[0:8]) -> LDS bf16 ----
  {
    const float qv = Q[i * M + t] + be0[t];
    float w0k[8];
#pragma unroll
    for (int k = 0; k < 8; ++k) w0k[k] = We0[k * M + t];
#pragma unroll 4
    for (int r = 0; r < JTILE; ++r) {
      const float pv = P[(j0 + r) * M + t];
      const f32x4 s0 = *(const f32x4*)&s_sqn[r][0];
      const f32x4 s1 = *(const f32x4*)&s_sqn[r][4];
      float acc = qv + pv;
      acc = fmaf(s0[0], w0k[0], acc); acc = fmaf(s0[1], w0k[1], acc);
      acc = fmaf(s0[2], w0k[2], acc); acc = fmaf(s0[3], w0k[3], acc);
      acc = fmaf(s1[0], w0k[4], acc); acc = fmaf(s1[1], w0k[5], acc);
      acc = fmaf(s1[2], w0k[6], acc); acc = fmaf(s1[3], w0k[7], acc);
      a_act[r * PITCH + t] = f2bf(silu_f(acc));
    }
  }
  // per-lane gate weights
  float wf[16];
#pragma unroll
  for (int nt = 0; nt < 16; ++nt) wf[nt] = Winf[nt * 16 + lnib];
  const float binf0 = binf[0];
  __syncthreads();

  f32x4 acc[2][16];

  // K-loop over LDS A rows (wave-private) x global pre-swizzled B frags
  auto run_gemm = [&](const unsigned short* __restrict__ B) {
#pragma unroll
    for (int kt = 0; kt < 8; ++kt) {
      const v8bf a0 = *(const v8bf*)&a_act[(r0 + lnib) * PITCH + kt * 32 + quad * 8];
      const v8bf a1 = *(const v8bf*)&a_act[(r0 + 16 + lnib) * PITCH + kt * 32 + quad * 8];
#pragma unroll
      for (int nt = 0; nt < 16; ++nt) {
        const v8bf bv = *(const v8bf*)&B[((kt * 16 + nt) * 64 + lane) * 8];
        acc[0][nt] = __builtin_amdgcn_mfma_f32_16x16x32_bf16(a0, bv, acc[0][nt], 0, 0, 0);
        acc[1][nt] = __builtin_amdgcn_mfma_f32_16x16x32_bf16(a1, bv, acc[1][nt], 0, 0, 0);
      }
    }
  };

  // ===== GEMM1: m = silu(a1 @ We1 + be1), diag mask, gate, write m =====
#pragma unroll
  for (int nt = 0; nt < 16; ++nt) {
    const float b = be1[nt * 16 + lnib];
    acc[0][nt] = (f32x4){b, b, b, b};
    acc[1][nt] = (f32x4){b, b, b, b};
  }
  run_gemm(wsB);

  {
    float gp[2][4] = {{0.f, 0.f, 0.f, 0.f}, {0.f, 0.f, 0.f, 0.f}};
#pragma unroll
    for (int rt = 0; rt < 2; ++rt) {
#pragma unroll
      for (int nt = 0; nt < 16; ++nt) {
#pragma unroll
        for (int reg = 0; reg < 4; ++reg) {
          float mv = silu_f(acc[rt][nt][reg]);
          const int row = r0 + rt * 16 + quad * 4 + reg;
          if (j0 + row == i) mv = 0.f;
          gp[rt][reg] = fmaf(mv, wf[nt], gp[rt][reg]);
          a_act[row * PITCH + nt * 16 + lnib] = f2bf(mv);
        }
      }
    }
#pragma unroll
    for (int rt = 0; rt < 2; ++rt) {
#pragma unroll
      for (int reg = 0; reg < 4; ++reg) {
        float g = gp[rt][reg];
        g += __shfl_xor(g, 1);
        g += __shfl_xor(g, 2);
        g += __shfl_xor(g, 4);
        g += __shfl_xor(g, 8);
        const float ev = 1.f / (1.f + __expf(-(g + binf0)));
        if (lnib == 0) s_e[r0 + rt * 16 + quad * 4 + reg] = ev;
      }
    }
  }
  __syncthreads();

  // ===== mi accumulation: thread t = channel t, sum over 128 local rows =====
  {
    float val = 0.f;
#pragma unroll 4
    for (int r = 0; r < JTILE; ++r)
      val = fmaf(bf2f(a_act[r * PITCH + t]), s_e[r], val);
    atomicAdd(&mi_acc[i * M + t], val);
  }
  __syncthreads();

  // ===== GEMM2: a2 = silu(m @ Wx0 + bx0) =====
#pragma unroll
  for (int nt = 0; nt < 16; ++nt) {
    const float b = bx0[nt * 16 + lnib];
    acc[0][nt] = (f32x4){b, b, b, b};
    acc[1][nt] = (f32x4){b, b, b, b};
  }
  run_gemm(wsB + 65536);
#pragma unroll
  for (int rt = 0; rt < 2; ++rt)
#pragma unroll
    for (int nt = 0; nt < 16; ++nt)
#pragma unroll
      for (int reg = 0; reg < 4; ++reg) {
        const int row = r0 + rt * 16 + quad * 4 + reg;
        a_act[row * PITCH + nt * 16 + lnib] = f2bf(silu_f(acc[rt][nt][reg]));
      }
  __syncthreads();

  // ===== GEMM3: a3 = silu(a2 @ Wx1 + bx1) =====
#pragma unroll
  for (int nt = 0; nt < 16; ++nt) {
    const float b = bx1[nt * 16 + lnib];
    acc[0][nt] = (f32x4){b, b, b, b};
    acc[1][nt] = (f32x4){b, b, b, b};
  }
  run_gemm(wsB + 131072);
#pragma unroll
  for (int rt = 0; rt < 2; ++rt)
#pragma unroll
    for (int nt = 0; nt < 16; ++nt)
#pragma unroll
      for (int reg = 0; reg < 4; ++reg) {
        const int row = r0 + rt * 16 + quad * 4 + reg;
        a_act[row * PITCH + nt * 16 + lnib] = f2bf(silu_f(acc[rt][nt][reg]));
      }
  __syncthreads();

  // ===== GEMM4: px = a3 @ Wxo + bxo (N padded to 16, cols 8..15 are zero) =====
  f32x4 px[2];
  {
    const float b = (lnib < 8) ? bxo[lnib] : 0.f;
    px[0] = (f32x4){b, b, b, b};
    px[1] = (f32x4){b, b, b, b};
    const unsigned short* B = wsB + 196608;
#pragma unroll
    for (int kt = 0; kt < 8; ++kt) {
      const v8bf a0 = *(const v8bf*)&a_act[(r0 + lnib) * PITCH + kt * 32 + quad * 8];
      const v8bf a1 = *(const v8bf*)&a_act[(r0 + 16 + lnib) * PITCH + kt * 32 + quad * 8];
      const v8bf bv = *(const v8bf*)&B[(kt * 64 + lane) * 8];
      px[0] = __builtin_amdgcn_mfma_f32_16x16x32_bf16(a0, bv, px[0], 0, 0, 0);
      px[1] = __builtin_amdgcn_mfma_f32_16x16x32_bf16(a1, bv, px[1], 0, 0, 0);
    }
  }

  // ===== shift: per-head normalized coordinate aggregation =====
  {
    const int hh = lnib & 7;   // lanes lnib>=8 compute zeros (B cols padded 0)
    const float xi0 = x[i * 24 + hh * 3 + 0];
    const float xi1 = x[i * 24 + hh * 3 + 1];
    const float xi2 = x[i * 24 + hh * 3 + 2];
    float p0 = 0.f, p1 = 0.f, p2 = 0.f;
#pragma unroll
    for (int rt = 0; rt < 2; ++rt) {
#pragma unroll
      for (int reg = 0; reg < 4; ++reg) {
        const int row = r0 + rt * 16 + quad * 4 + reg;
        const int jg = j0 + row;
        if (jg != i) {
          const float pxv = px[rt][reg];
          const float sq  = s_sqn[row][hh];
          const float f   = pxv / (sqrtf(sq + 1e-8f) + 1.f);  // NORM_CONST=1
          p0 = fmaf(x[jg * 24 + hh * 3 + 0] - xi0, f, p0);
          p1 = fmaf(x[jg * 24 + hh * 3 + 1] - xi1, f, p1);
          p2 = fmaf(x[jg * 24 + hh * 3 + 2] - xi2, f, p2);
        }
      }
    }
    p0 += __shfl_xor(p0, 16); p0 += __shfl_xor(p0, 32);
    p1 += __shfl_xor(p1, 16); p1 += __shfl_xor(p1, 32);
    p2 += __shfl_xor(p2, 16); p2 += __shfl_xor(p2, 32);
    if (lane < 8) {   // quad0, lnib<8: holds the wave-total for head hh
      atomicAdd(&shift_acc[i * 24 + hh * 3 + 0], p0);
      atomicAdd(&shift_acc[i * 24 + hh * 3 + 1], p1);
      atomicAdd(&shift_acc[i * 24 + hh * 3 + 2], p2);
    }
  }
}

// ---------------------------------------------------------------------------
__global__ void k_xout(const float* __restrict__ x, const float* __restrict__ shift,
                       float* __restrict__ out)
{
  const int idx = blockIdx.x * 256 + threadIdx.x;
  if (idx < N_NODES * NH * 3) out[idx] = x[idx] + shift[idx] * (1.f / 511.f);
}

__global__ __launch_bounds__(256) void k_hout(
    const float* __restrict__ h, const float* __restrict__ mi,
    const float* __restrict__ Wh0, const float* __restrict__ bh0,
    const float* __restrict__ Wh1, const float* __restrict__ bh1,
    const float* __restrict__ Who, const float* __restrict__ bho,
    float* __restrict__ out)
{
  const int i = blockIdx.x, t = threadIdx.x;
  __shared__ float s_in[M + HD];
  __shared__ float s_b[M];
  s_in[t] = mi[i * M + t];
  if (t < HD) s_in[M + t] = h[i * HD + t];
  __syncthreads();
  float acc = bh0[t];
  for (int k = 0; k < M + HD; ++k) acc = fmaf(s_in[k], Wh0[k * M + t], acc);
  s_b[t] = silu_f(acc);
  __syncthreads();
  float acc2 = bh1[t];
  for (int k = 0; k < M; ++k) acc2 = fmaf(s_b[k], Wh1[k * M + t], acc2);
  const float a1v = silu_f(acc2);
  __syncthreads();
  s_in[t] = a1v;
  __syncthreads();
  if (t < HD) {
    float o = bho[t];
    for (int k = 0; k < M; ++k) o = fmaf(s_in[k], Who[k * HD + t], o);
    out[i * HD + t] = h[i * HD + t] + o;
  }
}

// ---------------------------------------------------------------------------
extern "C" void kernel_launch(void* const* d_in, const int* in_sizes, int n_in,
                              void* d_out, int out_size, void* d_ws, size_t ws_size,
                              hipStream_t stream)
{
  const float* x    = (const float*)d_in[0];
  const float* h    = (const float*)d_in[1];
  const float* We0  = (const float*)d_in[2];
  const float* be0  = (const float*)d_in[3];
  const float* We1  = (const float*)d_in[4];
  const float* be1  = (const float*)d_in[5];
  const float* Winf = (const float*)d_in[6];
  const float* binf = (const float*)d_in[7];
  const float* Wx0  = (const float*)d_in[8];
  const float* bx0  = (const float*)d_in[9];
  const float* Wx1  = (const float*)d_in[10];
  const float* bx1  = (const float*)d_in[11];
  const float* Wxo  = (const float*)d_in[12];
  const float* bxo  = (const float*)d_in[13];
  const float* Wh0  = (const float*)d_in[14];
  const float* bh0  = (const float*)d_in[15];
  const float* Wh1  = (const float*)d_in[16];
  const float* bh1  = (const float*)d_in[17];
  const float* Who  = (const float*)d_in[18];
  const float* bho  = (const float*)d_in[19];

  float* out_x = (float*)d_out;                 // [512,8,3]
  float* out_h = out_x + N_NODES * NH * 3;      // [512,128]

  // ws layout (float units): mi[131072] | shift[12288] | P[131072] | Q[131072] | wsB(bf16, 200704)
  float* ws    = (float*)d_ws;
  float* mi    = ws;
  float* shift = ws + 131072;
  float* P     = ws + 143360;
  float* Q     = ws + 274432;
  unsigned short* wsB = (unsigned short*)(ws + 405504);

  hipMemsetAsync(mi, 0, (131072 + 12288) * sizeof(float), stream);

  k_prep<<<784, 256, 0, stream>>>(We1, Wx0, Wx1, Wxo, wsB);
  k_pq<<<N_NODES, 256, 0, stream>>>(x, h, We0, P, Q);
  k_edge<<<dim3(N_NODES, N_NODES / JTILE), 256, 0, stream>>>(
      x, P, Q, We0, be0, be1, Winf, binf, bx0, bx1, bxo, wsB, mi, shift);
  k_xout<<<(N_NODES * NH * 3 + 255) / 256, 256, 0, stream>>>(x, shift, out_x);
  k_hout<<<N_NODES, 256, 0, stream>>>(h, mi, Wh0, bh0, Wh1, bh1, Who, bho, out_h);
}

// Round 3
// 738.005 us; speedup vs baseline: 3.1109x; 1.0553x over previous
//
#include <hip/hip_runtime.h>
#include <math.h>

// EGCL_Multi on MFMA, barrier-free edge kernel.
// N=512 nodes, NH=8 heads, HD=128, M=256.
#define N_NODES 512
#define NH 8
#define HD 128
#define M 256
#define PITCH 264        // LDS activation row pitch in bf16 (528B: 16B-aligned)
#define JTILE 128        // edges (j) per block = 4 waves x 32
#define RPW 32           // rows per wave

typedef __bf16 v8bf __attribute__((ext_vector_type(8)));
typedef float f32x4 __attribute__((ext_vector_type(4)));
typedef unsigned short us4v __attribute__((ext_vector_type(4)));

__device__ __forceinline__ float silu_f(float v) { return v / (1.f + __expf(-v)); }
__device__ __forceinline__ unsigned short f2bf(float f) {
  unsigned u = __float_as_uint(f);
  u += 0x7fffu + ((u >> 16) & 1u);
  return (unsigned short)(u >> 16);
}

// ---------------------------------------------------------------------------
// Weight prep: fp32 [K,N] row-major -> bf16 MFMA-B-fragment order.
// dst[((kt*NT + nt)*64 + lane)*8 + j] = W[kt*32 + (lane>>4)*8 + j][nt*16 + (lane&15)]
// We1 @0, Wx0 @65536, Wx1 @131072, Wxo (256x8 pad->16) @196608.
// ---------------------------------------------------------------------------
__global__ __launch_bounds__(256) void k_prep(
    const float* __restrict__ We1, const float* __restrict__ Wx0,
    const float* __restrict__ Wx1, const float* __restrict__ Wxo,
    unsigned short* __restrict__ wsB)
{
  const int gid = blockIdx.x * 256 + threadIdx.x;
  if (gid >= 200704) return;
  float val;
  if (gid < 196608) {
    const int layer = gid >> 16;
    const int i2 = gid & 65535;
    const int j = i2 & 7, lane = (i2 >> 3) & 63, nt = (i2 >> 9) & 15, kt = i2 >> 13;
    const int k = kt * 32 + (lane >> 4) * 8 + j;
    const int n = nt * 16 + (lane & 15);
    const float* W = (layer == 0) ? We1 : (layer == 1) ? Wx0 : Wx1;
    val = W[k * 256 + n];
  } else {
    const int i2 = gid - 196608;
    const int j = i2 & 7, lane = (i2 >> 3) & 63, kt = (i2 >> 9) & 7;
    const int k = kt * 32 + (lane >> 4) * 8 + j;
    const int n = lane & 15;
    val = (n < 8) ? Wxo[k * 8 + n] : 0.f;
  }
  wsB[gid] = f2bf(val);
}

// ---------------------------------------------------------------------------
// Per-node P/Q precompute (layer-0 algebraic split), fp32.
// ---------------------------------------------------------------------------
__global__ __launch_bounds__(256) void k_pq(
    const float* __restrict__ x, const float* __restrict__ h,
    const float* __restrict__ We0,
    float* __restrict__ P, float* __restrict__ Q)
{
  const int i = blockIdx.x, t = threadIdx.x;
  __shared__ float s_x[24];
  __shared__ float s_hc[192];
  if (t < 24) s_x[t] = x[i * 24 + t];
  __syncthreads();
  if (t < HD) {
    s_hc[t] = h[i * HD + t];
  } else if (t < 192) {
    const int p = t - HD, a = p >> 3, b = p & 7;
    float s = 0.f;
#pragma unroll
    for (int d = 0; d < 3; ++d) {
      const float dx = s_x[a * 3 + d] - s_x[b * 3 + d];
      s = fmaf(dx, dx, s);
    }
    s_hc[t] = s;
  }
  __syncthreads();
  float p = 0.f, q = 0.f;
  for (int k = 0; k < 192; ++k) {
    const float hv = s_hc[k];
    p = fmaf(hv, We0[(8 + k) * M + t], p);
    q = fmaf(hv, We0[(200 + k) * M + t], q);
  }
  P[i * M + t] = p;
  Q[i * M + t] = q;
}

// ---------------------------------------------------------------------------
// Fused edge pipeline, ZERO barriers: every stage is wave-private.
// Block = (i, 128-j tile); wave w owns rows [32w, 32w+32) end-to-end.
// ---------------------------------------------------------------------------
__global__ __launch_bounds__(256, 2) void k_edge(
    const float* __restrict__ x,
    const float* __restrict__ P, const float* __restrict__ Q,
    const float* __restrict__ We0, const float* __restrict__ be0,
    const float* __restrict__ be1,
    const float* __restrict__ Winf, const float* __restrict__ binf,
    const float* __restrict__ bx0, const float* __restrict__ bx1,
    const float* __restrict__ bxo,
    const unsigned short* __restrict__ wsB,
    float* __restrict__ mi_acc, float* __restrict__ shift_acc)
{
  const int i  = blockIdx.x;
  const int j0 = blockIdx.y * JTILE;
  const int t  = threadIdx.x;
  const int lane = t & 63, wave = t >> 6;
  const int lnib = lane & 15, quad = lane >> 4;
  const int r0 = wave * RPW;       // block-local row base
  const int jw = j0 + r0;          // first edge (j) of this wave

  __shared__ __align__(16) unsigned short a_act[JTILE * PITCH];  // 67.6 KB
  __shared__ __align__(16) float s_sqn[JTILE][8];                // 4 KB

  // ---- sqn for this wave's 32 rows (wave-private LDS region) ----
#pragma unroll
  for (int kk = 0; kk < 4; ++kk) {
    const int idx = kk * 64 + lane;          // 0..255 = 32 rows x 8 heads
    const int r = idx >> 3, hh = idx & 7;
    const int j = jw + r;
    float s = 0.f;
#pragma unroll
    for (int d = 0; d < 3; ++d) {
      const float dx = x[j * 24 + hh * 3 + d] - x[i * 24 + hh * 3 + d];
      s = fmaf(dx, dx, s);
    }
    s_sqn[r0 + r][hh] = s;
  }

  // ---- stage 0: a1 = silu(be0 + Q[i] + P[j] + sqn . We0[0:8]), wave-private ----
  {
    const int c0 = lane * 4;                 // 64 lanes x 4 = 256 channels
    const f32x4 qv = *(const f32x4*)&Q[i * M + c0];
    const f32x4 b0 = *(const f32x4*)&be0[c0];
    const f32x4 base = qv + b0;
    f32x4 w0k[8];
#pragma unroll
    for (int k = 0; k < 8; ++k) w0k[k] = *(const f32x4*)&We0[k * M + c0];
#pragma unroll 4
    for (int r = 0; r < RPW; ++r) {
      const f32x4 pv = *(const f32x4*)&P[(jw + r) * M + c0];
      f32x4 a = base + pv;
#pragma unroll
      for (int k = 0; k < 8; ++k) {
        const float sv = s_sqn[r0 + r][k];   // broadcast (same addr all lanes)
        a[0] = fmaf(sv, w0k[k][0], a[0]);
        a[1] = fmaf(sv, w0k[k][1], a[1]);
        a[2] = fmaf(sv, w0k[k][2], a[2]);
        a[3] = fmaf(sv, w0k[k][3], a[3]);
      }
      us4v pk;
      pk[0] = f2bf(silu_f(a[0])); pk[1] = f2bf(silu_f(a[1]));
      pk[2] = f2bf(silu_f(a[2])); pk[3] = f2bf(silu_f(a[3]));
      *(us4v*)&a_act[(r0 + r) * PITCH + c0] = pk;   // 8B store
    }
  }

  // gate weights per lane
  float wf[16];
#pragma unroll
  for (int nt = 0; nt < 16; ++nt) wf[nt] = Winf[nt * 16 + lnib];
  const float binf0 = binf[0];

  f32x4 acc[2][16];

  auto run_gemm = [&](const unsigned short* __restrict__ B) {
#pragma unroll
    for (int kt = 0; kt < 8; ++kt) {
      const v8bf a0 = *(const v8bf*)&a_act[(r0 + lnib) * PITCH + kt * 32 + quad * 8];
      const v8bf a1 = *(const v8bf*)&a_act[(r0 + 16 + lnib) * PITCH + kt * 32 + quad * 8];
#pragma unroll
      for (int nt = 0; nt < 16; ++nt) {
        const v8bf bv = *(const v8bf*)&B[((kt * 16 + nt) * 64 + lane) * 8];
        acc[0][nt] = __builtin_amdgcn_mfma_f32_16x16x32_bf16(a0, bv, acc[0][nt], 0, 0, 0);
        acc[1][nt] = __builtin_amdgcn_mfma_f32_16x16x32_bf16(a1, bv, acc[1][nt], 0, 0, 0);
      }
    }
  };

  // ===== GEMM1: m = silu(a1 @ We1 + be1), diag mask, gate, mi — all wave-local =====
#pragma unroll
  for (int nt = 0; nt < 16; ++nt) {
    const float b = be1[nt * 16 + lnib];
    acc[0][nt] = (f32x4){b, b, b, b};
    acc[1][nt] = (f32x4){b, b, b, b};
  }
  run_gemm(wsB);

  {
    float ge[2][4] = {{0.f, 0.f, 0.f, 0.f}, {0.f, 0.f, 0.f, 0.f}};
#pragma unroll
    for (int rt = 0; rt < 2; ++rt)
#pragma unroll
      for (int nt = 0; nt < 16; ++nt)
#pragma unroll
        for (int reg = 0; reg < 4; ++reg) {
          float v = silu_f(acc[rt][nt][reg]);
          const int row = r0 + rt * 16 + quad * 4 + reg;
          if (j0 + row == i) v = 0.f;
          acc[rt][nt][reg] = v;              // keep m for mi reduction
          a_act[row * PITCH + nt * 16 + lnib] = f2bf(v);
          ge[rt][reg] = fmaf(v, wf[nt], ge[rt][reg]);
        }
    // gate: butterfly over the 16 lnib lanes -> every lane holds e for its rows
#pragma unroll
    for (int rt = 0; rt < 2; ++rt)
#pragma unroll
      for (int reg = 0; reg < 4; ++reg) {
        float g = ge[rt][reg];
        g += __shfl_xor(g, 1);
        g += __shfl_xor(g, 2);
        g += __shfl_xor(g, 4);
        g += __shfl_xor(g, 8);
        ge[rt][reg] = 1.f / (1.f + __expf(-(g + binf0)));
      }
    // mi: in-register reduce over this wave's 32 rows, cross-quad butterfly, atomics
#pragma unroll
    for (int nt = 0; nt < 16; ++nt) {
      float p = 0.f;
#pragma unroll
      for (int rt = 0; rt < 2; ++rt)
#pragma unroll
        for (int reg = 0; reg < 4; ++reg)
          p = fmaf(acc[rt][nt][reg], ge[rt][reg], p);
      p += __shfl_xor(p, 16);
      p += __shfl_xor(p, 32);
      if (quad == 0) atomicAdd(&mi_acc[i * M + nt * 16 + lnib], p);
    }
  }

  // ===== GEMM2: a2 = silu(m @ Wx0 + bx0) =====
#pragma unroll
  for (int nt = 0; nt < 16; ++nt) {
    const float b = bx0[nt * 16 + lnib];
    acc[0][nt] = (f32x4){b, b, b, b};
    acc[1][nt] = (f32x4){b, b, b, b};
  }
  run_gemm(wsB + 65536);
#pragma unroll
  for (int rt = 0; rt < 2; ++rt)
#pragma unroll
    for (int nt = 0; nt < 16; ++nt)
#pragma unroll
      for (int reg = 0; reg < 4; ++reg) {
        const int row = r0 + rt * 16 + quad * 4 + reg;
        a_act[row * PITCH + nt * 16 + lnib] = f2bf(silu_f(acc[rt][nt][reg]));
      }

  // ===== GEMM3: a3 = silu(a2 @ Wx1 + bx1) =====
#pragma unroll
  for (int nt = 0; nt < 16; ++nt) {
    const float b = bx1[nt * 16 + lnib];
    acc[0][nt] = (f32x4){b, b, b, b};
    acc[1][nt] = (f32x4){b, b, b, b};
  }
  run_gemm(wsB + 131072);
#pragma unroll
  for (int rt = 0; rt < 2; ++rt)
#pragma unroll
    for (int nt = 0; nt < 16; ++nt)
#pragma unroll
      for (int reg = 0; reg < 4; ++reg) {
        const int row = r0 + rt * 16 + quad * 4 + reg;
        a_act[row * PITCH + nt * 16 + lnib] = f2bf(silu_f(acc[rt][nt][reg]));
      }

  // ===== GEMM4: px = a3 @ Wxo + bxo (N padded to 16; cols 8..15 zero) =====
  f32x4 px[2];
  {
    const float b = (lnib < 8) ? bxo[lnib] : 0.f;
    px[0] = (f32x4){b, b, b, b};
    px[1] = (f32x4){b, b, b, b};
    const unsigned short* B = wsB + 196608;
#pragma unroll
    for (int kt = 0; kt < 8; ++kt) {
      const v8bf a0 = *(const v8bf*)&a_act[(r0 + lnib) * PITCH + kt * 32 + quad * 8];
      const v8bf a1 = *(const v8bf*)&a_act[(r0 + 16 + lnib) * PITCH + kt * 32 + quad * 8];
      const v8bf bv = *(const v8bf*)&B[(kt * 64 + lane) * 8];
      px[0] = __builtin_amdgcn_mfma_f32_16x16x32_bf16(a0, bv, px[0], 0, 0, 0);
      px[1] = __builtin_amdgcn_mfma_f32_16x16x32_bf16(a1, bv, px[1], 0, 0, 0);
    }
  }

  // ===== shift: per-head normalized coordinate aggregation (wave-local) =====
  {
    const int hh = lnib & 7;   // lanes lnib>=8 hold zero px (padded B cols)
    const float xi0 = x[i * 24 + hh * 3 + 0];
    const float xi1 = x[i * 24 + hh * 3 + 1];
    const float xi2 = x[i * 24 + hh * 3 + 2];
    float p0 = 0.f, p1 = 0.f, p2 = 0.f;
#pragma unroll
    for (int rt = 0; rt < 2; ++rt)
#pragma unroll
      for (int reg = 0; reg < 4; ++reg) {
        const int row = r0 + rt * 16 + quad * 4 + reg;
        const int jg = j0 + row;
        if (jg != i) {
          const float pxv = px[rt][reg];
          const float sq  = s_sqn[row][hh];
          const float f   = pxv / (sqrtf(sq + 1e-8f) + 1.f);  // NORM_CONST=1
          p0 = fmaf(x[jg * 24 + hh * 3 + 0] - xi0, f, p0);
          p1 = fmaf(x[jg * 24 + hh * 3 + 1] - xi1, f, p1);
          p2 = fmaf(x[jg * 24 + hh * 3 + 2] - xi2, f, p2);
        }
      }
    p0 += __shfl_xor(p0, 16); p0 += __shfl_xor(p0, 32);
    p1 += __shfl_xor(p1, 16); p1 += __shfl_xor(p1, 32);
    p2 += __shfl_xor(p2, 16); p2 += __shfl_xor(p2, 32);
    if (lane < 8) {
      atomicAdd(&shift_acc[i * 24 + hh * 3 + 0], p0);
      atomicAdd(&shift_acc[i * 24 + hh * 3 + 1], p1);
      atomicAdd(&shift_acc[i * 24 + hh * 3 + 2], p2);
    }
  }
}

// ---------------------------------------------------------------------------
__global__ void k_xout(const float* __restrict__ x, const float* __restrict__ shift,
                       float* __restrict__ out)
{
  const int idx = blockIdx.x * 256 + threadIdx.x;
  if (idx < N_NODES * NH * 3) out[idx] = x[idx] + shift[idx] * (1.f / 511.f);
}

__global__ __launch_bounds__(256) void k_hout(
    const float* __restrict__ h, const float* __restrict__ mi,
    const float* __restrict__ Wh0, const float* __restrict__ bh0,
    const float* __restrict__ Wh1, const float* __restrict__ bh1,
    const float* __restrict__ Who, const float* __restrict__ bho,
    float* __restrict__ out)
{
  const int i = blockIdx.x, t = threadIdx.x;
  __shared__ float s_in[M + HD];
  __shared__ float s_b[M];
  s_in[t] = mi[i * M + t];
  if (t < HD) s_in[M + t] = h[i * HD + t];
  __syncthreads();
  float acc = bh0[t];
  for (int k = 0; k < M + HD; ++k) acc = fmaf(s_in[k], Wh0[k * M + t], acc);
  s_b[t] = silu_f(acc);
  __syncthreads();
  float acc2 = bh1[t];
  for (int k = 0; k < M; ++k) acc2 = fmaf(s_b[k], Wh1[k * M + t], acc2);
  const float a1v = silu_f(acc2);
  __syncthreads();
  s_in[t] = a1v;
  __syncthreads();
  if (t < HD) {
    float o = bho[t];
    for (int k = 0; k < M; ++k) o = fmaf(s_in[k], Who[k * HD + t], o);
    out[i * HD + t] = h[i * HD + t] + o;
  }
}

// ---------------------------------------------------------------------------
extern "C" void kernel_launch(void* const* d_in, const int* in_sizes, int n_in,
                              void* d_out, int out_size, void* d_ws, size_t ws_size,
                              hipStream_t stream)
{
  const float* x    = (const float*)d_in[0];
  const float* h    = (const float*)d_in[1];
  const float* We0  = (const float*)d_in[2];
  const float* be0  = (const float*)d_in[3];
  const float* We1  = (const float*)d_in[4];
  const float* be1  = (const float*)d_in[5];
  const float* Winf = (const float*)d_in[6];
  const float* binf = (const float*)d_in[7];
  const float* Wx0  = (const float*)d_in[8];
  const float* bx0  = (const float*)d_in[9];
  const float* Wx1  = (const float*)d_in[10];
  const float* bx1  = (const float*)d_in[11];
  const float* Wxo  = (const float*)d_in[12];
  const float* bxo  = (const float*)d_in[13];
  const float* Wh0  = (const float*)d_in[14];
  const float* bh0  = (const float*)d_in[15];
  const float* Wh1  = (const float*)d_in[16];
  const float* bh1  = (const float*)d_in[17];
  const float* Who  = (const float*)d_in[18];
  const float* bho  = (const float*)d_in[19];

  float* out_x = (float*)d_out;                 // [512,8,3]
  float* out_h = out_x + N_NODES * NH * 3;      // [512,128]

  // ws layout (float units): mi[131072] | shift[12288] | P[131072] | Q[131072] | wsB(bf16)
  float* ws    = (float*)d_ws;
  float* mi    = ws;
  float* shift = ws + 131072;
  float* P     = ws + 143360;
  float* Q     = ws + 274432;
  unsigned short* wsB = (unsigned short*)(ws + 405504);

  hipMemsetAsync(mi, 0, (131072 + 12288) * sizeof(float), stream);

  k_prep<<<784, 256, 0, stream>>>(We1, Wx0, Wx1, Wxo, wsB);
  k_pq<<<N_NODES, 256, 0, stream>>>(x, h, We0, P, Q);
  k_edge<<<dim3(N_NODES, N_NODES / JTILE), 256, 0, stream>>>(
      x, P, Q, We0, be0, be1, Winf, binf, bx0, bx1, bxo, wsB, mi, shift);
  k_xout<<<(N_NODES * NH * 3 + 255) / 256, 256, 0, stream>>>(x, shift, out_x);
  k_hout<<<N_NODES, 256, 0, stream>>>(h, mi, Wh0, bh0, Wh1, bh1, Who, bho, out_h);
}

// Round 4
// 554.265 us; speedup vs baseline: 4.1421x; 1.3315x over previous
//
#include <hip/hip_runtime.h>
#include <math.h>

// EGCL_Multi on MFMA, barrier-free, spill-free edge kernel.
// N=512 nodes, NH=8 heads, HD=128, M=256.
#define N_NODES 512
#define NH 8
#define HD 128
#define M 256
#define PITCH 264        // LDS activation row pitch in bf16 (528B)
#define JTILE 64         // edges (j) per block = 4 waves x 16
#define RPW 16           // rows per wave

typedef __bf16 v8bf __attribute__((ext_vector_type(8)));
typedef float f32x4 __attribute__((ext_vector_type(4)));
typedef unsigned short us4v __attribute__((ext_vector_type(4)));

__device__ __forceinline__ float silu_f(float v) { return v / (1.f + __expf(-v)); }
__device__ __forceinline__ unsigned short f2bf(float f) {
  unsigned u = __float_as_uint(f);
  u += 0x7fffu + ((u >> 16) & 1u);
  return (unsigned short)(u >> 16);
}
__device__ __forceinline__ float bf2f(unsigned short s) {
  return __uint_as_float(((unsigned)s) << 16);
}

// ---------------------------------------------------------------------------
// Weight prep: fp32 [K,N] row-major -> bf16 MFMA-B-fragment order.
// dst[((kt*16 + nt)*64 + lane)*8 + j] = W[kt*32 + (lane>>4)*8 + j][nt*16 + (lane&15)]
// We1 @0, Wx0 @65536, Wx1 @131072, Wxo (256x8 pad->16) @196608.
// ---------------------------------------------------------------------------
__global__ __launch_bounds__(256) void k_prep(
    const float* __restrict__ We1, const float* __restrict__ Wx0,
    const float* __restrict__ Wx1, const float* __restrict__ Wxo,
    unsigned short* __restrict__ wsB)
{
  const int gid = blockIdx.x * 256 + threadIdx.x;
  if (gid >= 200704) return;
  float val;
  if (gid < 196608) {
    const int layer = gid >> 16;
    const int i2 = gid & 65535;
    const int j = i2 & 7, lane = (i2 >> 3) & 63, nt = (i2 >> 9) & 15, kt = i2 >> 13;
    const int k = kt * 32 + (lane >> 4) * 8 + j;
    const int n = nt * 16 + (lane & 15);
    const float* W = (layer == 0) ? We1 : (layer == 1) ? Wx0 : Wx1;
    val = W[k * 256 + n];
  } else {
    const int i2 = gid - 196608;
    const int j = i2 & 7, lane = (i2 >> 3) & 63, kt = (i2 >> 9) & 7;
    const int k = kt * 32 + (lane >> 4) * 8 + j;
    const int n = lane & 15;
    val = (n < 8) ? Wxo[k * 8 + n] : 0.f;
  }
  wsB[gid] = f2bf(val);
}

// ---------------------------------------------------------------------------
// Per-node P/Q precompute (layer-0 algebraic split), fp32.
// ---------------------------------------------------------------------------
__global__ __launch_bounds__(256) void k_pq(
    const float* __restrict__ x, const float* __restrict__ h,
    const float* __restrict__ We0,
    float* __restrict__ P, float* __restrict__ Q)
{
  const int i = blockIdx.x, t = threadIdx.x;
  __shared__ float s_x[24];
  __shared__ float s_hc[192];
  if (t < 24) s_x[t] = x[i * 24 + t];
  __syncthreads();
  if (t < HD) {
    s_hc[t] = h[i * HD + t];
  } else if (t < 192) {
    const int p = t - HD, a = p >> 3, b = p & 7;
    float s = 0.f;
#pragma unroll
    for (int d = 0; d < 3; ++d) {
      const float dx = s_x[a * 3 + d] - s_x[b * 3 + d];
      s = fmaf(dx, dx, s);
    }
    s_hc[t] = s;
  }
  __syncthreads();
  float p = 0.f, q = 0.f;
  for (int k = 0; k < 192; ++k) {
    const float hv = s_hc[k];
    p = fmaf(hv, We0[(8 + k) * M + t], p);
    q = fmaf(hv, We0[(200 + k) * M + t], q);
  }
  P[i * M + t] = p;
  Q[i * M + t] = q;
}

// ---------------------------------------------------------------------------
// Fused edge pipeline: zero barriers, wave-private rows, acc = 64 regs only.
// Block = (i, 64-j tile); wave w owns rows [16w, 16w+16) end-to-end.
// ---------------------------------------------------------------------------
__global__ __launch_bounds__(256, 2) void k_edge(
    const float* __restrict__ x,
    const float* __restrict__ P, const float* __restrict__ Q,
    const float* __restrict__ We0, const float* __restrict__ be0,
    const float* __restrict__ be1,
    const float* __restrict__ Winf, const float* __restrict__ binf,
    const float* __restrict__ bx0, const float* __restrict__ bx1,
    const float* __restrict__ bxo,
    const unsigned short* __restrict__ wsB,
    float* __restrict__ mi_acc, float* __restrict__ shift_acc)
{
  const int i  = blockIdx.x;
  const int j0 = blockIdx.y * JTILE;
  const int t  = threadIdx.x;
  const int lane = t & 63, wave = t >> 6;
  const int lnib = lane & 15, quad = lane >> 4;
  const int r0 = wave * RPW;       // block-local row base
  const int jw = j0 + r0;          // first edge (j) of this wave

  __shared__ __align__(16) unsigned short a_act[JTILE * PITCH];  // 33.8 KB
  __shared__ __align__(16) float s_sqn[JTILE][8];                // 2 KB
  __shared__ float s_e[JTILE];                                   // 256 B

  // ---- sqn for this wave's 16 rows (wave-private LDS region) ----
#pragma unroll
  for (int kk = 0; kk < 2; ++kk) {
    const int idx = kk * 64 + lane;          // 0..127 = 16 rows x 8 heads
    const int r = idx >> 3, hh = idx & 7;
    const int j = jw + r;
    float s = 0.f;
#pragma unroll
    for (int d = 0; d < 3; ++d) {
      const float dx = x[j * 24 + hh * 3 + d] - x[i * 24 + hh * 3 + d];
      s = fmaf(dx, dx, s);
    }
    s_sqn[r0 + r][hh] = s;
  }

  // ---- stage 0: a1 = silu(be0 + Q[i] + P[j] + sqn . We0[0:8]) -> LDS bf16 ----
  {
    const int c0 = lane * 4;                 // 64 lanes x 4 = 256 channels
    const f32x4 qv = *(const f32x4*)&Q[i * M + c0];
    const f32x4 b0 = *(const f32x4*)&be0[c0];
    const f32x4 base = qv + b0;
    f32x4 w0k[8];
#pragma unroll
    for (int k = 0; k < 8; ++k) w0k[k] = *(const f32x4*)&We0[k * M + c0];
#pragma unroll 4
    for (int r = 0; r < RPW; ++r) {
      const f32x4 pv = *(const f32x4*)&P[(jw + r) * M + c0];
      f32x4 a = base + pv;
#pragma unroll
      for (int k = 0; k < 8; ++k) {
        const float sv = s_sqn[r0 + r][k];   // broadcast
        a[0] = fmaf(sv, w0k[k][0], a[0]);
        a[1] = fmaf(sv, w0k[k][1], a[1]);
        a[2] = fmaf(sv, w0k[k][2], a[2]);
        a[3] = fmaf(sv, w0k[k][3], a[3]);
      }
      us4v pk;
      pk[0] = f2bf(silu_f(a[0])); pk[1] = f2bf(silu_f(a[1]));
      pk[2] = f2bf(silu_f(a[2])); pk[3] = f2bf(silu_f(a[3]));
      *(us4v*)&a_act[(r0 + r) * PITCH + c0] = pk;
    }
  }

  const float binf0 = binf[0];

  f32x4 acc[16];                             // 64 floats -> AGPR-resident

  auto run_gemm = [&](const unsigned short* __restrict__ B) {
#pragma unroll
    for (int kt = 0; kt < 8; ++kt) {
      const v8bf a0 = *(const v8bf*)&a_act[(r0 + lnib) * PITCH + kt * 32 + quad * 8];
#pragma unroll
      for (int nt = 0; nt < 16; ++nt) {
        const v8bf bv = *(const v8bf*)&B[((kt * 16 + nt) * 64 + lane) * 8];
        acc[nt] = __builtin_amdgcn_mfma_f32_16x16x32_bf16(a0, bv, acc[nt], 0, 0, 0);
      }
    }
  };

  // ===== GEMM1: m = silu(a1 @ We1 + be1), diag mask, gate -> streaming epi =====
#pragma unroll
  for (int nt = 0; nt < 16; ++nt) {
    const float b = be1[nt * 16 + lnib];
    acc[nt] = (f32x4){b, b, b, b};
  }
  run_gemm(wsB);
  {
    float ge[4] = {0.f, 0.f, 0.f, 0.f};
#pragma unroll
    for (int nt = 0; nt < 16; ++nt) {
      const float wfv = Winf[nt * 16 + lnib];  // L1-hot, avoids 16 live regs
#pragma unroll
      for (int reg = 0; reg < 4; ++reg) {
        float v = silu_f(acc[nt][reg]);
        const int row = r0 + quad * 4 + reg;
        if (j0 + row == i) v = 0.f;
        a_act[row * PITCH + nt * 16 + lnib] = f2bf(v);
        ge[reg] = fmaf(v, wfv, ge[reg]);
      }
    }
#pragma unroll
    for (int reg = 0; reg < 4; ++reg) {
      float g = ge[reg];
      g += __shfl_xor(g, 1);
      g += __shfl_xor(g, 2);
      g += __shfl_xor(g, 4);
      g += __shfl_xor(g, 8);
      const float ev = 1.f / (1.f + __expf(-(g + binf0)));
      if (lnib == 0) s_e[r0 + quad * 4 + reg] = ev;
    }
  }

  // ===== mi: wave-private LDS re-read of m, scaled by e[r] =====
  {
    const int c0 = lane * 4;
    f32x4 mip = (f32x4){0.f, 0.f, 0.f, 0.f};
#pragma unroll
    for (int r = 0; r < RPW; ++r) {
      const us4v mv = *(const us4v*)&a_act[(r0 + r) * PITCH + c0];
      const float ev = s_e[r0 + r];          // broadcast
      mip[0] = fmaf(bf2f(mv[0]), ev, mip[0]);
      mip[1] = fmaf(bf2f(mv[1]), ev, mip[1]);
      mip[2] = fmaf(bf2f(mv[2]), ev, mip[2]);
      mip[3] = fmaf(bf2f(mv[3]), ev, mip[3]);
    }
    atomicAdd(&mi_acc[i * M + c0 + 0], mip[0]);
    atomicAdd(&mi_acc[i * M + c0 + 1], mip[1]);
    atomicAdd(&mi_acc[i * M + c0 + 2], mip[2]);
    atomicAdd(&mi_acc[i * M + c0 + 3], mip[3]);
  }

  // ===== GEMM2: a2 = silu(m @ Wx0 + bx0) =====
#pragma unroll
  for (int nt = 0; nt < 16; ++nt) {
    const float b = bx0[nt * 16 + lnib];
    acc[nt] = (f32x4){b, b, b, b};
  }
  run_gemm(wsB + 65536);
#pragma unroll
  for (int nt = 0; nt < 16; ++nt)
#pragma unroll
    for (int reg = 0; reg < 4; ++reg) {
      const int row = r0 + quad * 4 + reg;
      a_act[row * PITCH + nt * 16 + lnib] = f2bf(silu_f(acc[nt][reg]));
    }

  // ===== GEMM3: a3 = silu(a2 @ Wx1 + bx1) =====
#pragma unroll
  for (int nt = 0; nt < 16; ++nt) {
    const float b = bx1[nt * 16 + lnib];
    acc[nt] = (f32x4){b, b, b, b};
  }
  run_gemm(wsB + 131072);
#pragma unroll
  for (int nt = 0; nt < 16; ++nt)
#pragma unroll
    for (int reg = 0; reg < 4; ++reg) {
      const int row = r0 + quad * 4 + reg;
      a_act[row * PITCH + nt * 16 + lnib] = f2bf(silu_f(acc[nt][reg]));
    }

  // ===== GEMM4: px = a3 @ Wxo + bxo (N padded to 16; cols 8..15 zero) =====
  f32x4 px;
  {
    const float b = (lnib < 8) ? bxo[lnib] : 0.f;
    px = (f32x4){b, b, b, b};
    const unsigned short* B = wsB + 196608;
#pragma unroll
    for (int kt = 0; kt < 8; ++kt) {
      const v8bf a0 = *(const v8bf*)&a_act[(r0 + lnib) * PITCH + kt * 32 + quad * 8];
      const v8bf bv = *(const v8bf*)&B[(kt * 64 + lane) * 8];
      px = __builtin_amdgcn_mfma_f32_16x16x32_bf16(a0, bv, px, 0, 0, 0);
    }
  }

  // ===== shift: per-head normalized coordinate aggregation (wave-local) =====
  {
    const int hh = lnib & 7;   // lanes lnib>=8 hold zero px (padded B cols)
    const float xi0 = x[i * 24 + hh * 3 + 0];
    const float xi1 = x[i * 24 + hh * 3 + 1];
    const float xi2 = x[i * 24 + hh * 3 + 2];
    float p0 = 0.f, p1 = 0.f, p2 = 0.f;
#pragma unroll
    for (int reg = 0; reg < 4; ++reg) {
      const int row = r0 + quad * 4 + reg;
      const int jg = j0 + row;
      if (jg != i) {
        const float pxv = px[reg];
        const float sq  = s_sqn[row][hh];
        const float f   = pxv / (sqrtf(sq + 1e-8f) + 1.f);  // NORM_CONST=1
        p0 = fmaf(x[jg * 24 + hh * 3 + 0] - xi0, f, p0);
        p1 = fmaf(x[jg * 24 + hh * 3 + 1] - xi1, f, p1);
        p2 = fmaf(x[jg * 24 + hh * 3 + 2] - xi2, f, p2);
      }
    }
    p0 += __shfl_xor(p0, 16); p0 += __shfl_xor(p0, 32);
    p1 += __shfl_xor(p1, 16); p1 += __shfl_xor(p1, 32);
    p2 += __shfl_xor(p2, 16); p2 += __shfl_xor(p2, 32);
    if (lane < 8) {
      atomicAdd(&shift_acc[i * 24 + hh * 3 + 0], p0);
      atomicAdd(&shift_acc[i * 24 + hh * 3 + 1], p1);
      atomicAdd(&shift_acc[i * 24 + hh * 3 + 2], p2);
    }
  }
}

// ---------------------------------------------------------------------------
__global__ void k_xout(const float* __restrict__ x, const float* __restrict__ shift,
                       float* __restrict__ out)
{
  const int idx = blockIdx.x * 256 + threadIdx.x;
  if (idx < N_NODES * NH * 3) out[idx] = x[idx] + shift[idx] * (1.f / 511.f);
}

__global__ __launch_bounds__(256) void k_hout(
    const float* __restrict__ h, const float* __restrict__ mi,
    const float* __restrict__ Wh0, const float* __restrict__ bh0,
    const float* __restrict__ Wh1, const float* __restrict__ bh1,
    const float* __restrict__ Who, const float* __restrict__ bho,
    float* __restrict__ out)
{
  const int i = blockIdx.x, t = threadIdx.x;
  __shared__ float s_in[M + HD];
  __shared__ float s_b[M];
  s_in[t] = mi[i * M + t];
  if (t < HD) s_in[M + t] = h[i * HD + t];
  __syncthreads();
  float acc = bh0[t];
  for (int k = 0; k < M + HD; ++k) acc = fmaf(s_in[k], Wh0[k * M + t], acc);
  s_b[t] = silu_f(acc);
  __syncthreads();
  float acc2 = bh1[t];
  for (int k = 0; k < M; ++k) acc2 = fmaf(s_b[k], Wh1[k * M + t], acc2);
  const float a1v = silu_f(acc2);
  __syncthreads();
  s_in[t] = a1v;
  __syncthreads();
  if (t < HD) {
    float o = bho[t];
    for (int k = 0; k < M; ++k) o = fmaf(s_in[k], Who[k * HD + t], o);
    out[i * HD + t] = h[i * HD + t] + o;
  }
}

// ---------------------------------------------------------------------------
extern "C" void kernel_launch(void* const* d_in, const int* in_sizes, int n_in,
                              void* d_out, int out_size, void* d_ws, size_t ws_size,
                              hipStream_t stream)
{
  const float* x    = (const float*)d_in[0];
  const float* h    = (const float*)d_in[1];
  const float* We0  = (const float*)d_in[2];
  const float* be0  = (const float*)d_in[3];
  const float* We1  = (const float*)d_in[4];
  const float* be1  = (const float*)d_in[5];
  const float* Winf = (const float*)d_in[6];
  const float* binf = (const float*)d_in[7];
  const float* Wx0  = (const float*)d_in[8];
  const float* bx0  = (const float*)d_in[9];
  const float* Wx1  = (const float*)d_in[10];
  const float* bx1  = (const float*)d_in[11];
  const float* Wxo  = (const float*)d_in[12];
  const float* bxo  = (const float*)d_in[13];
  const float* Wh0  = (const float*)d_in[14];
  const float* bh0  = (const float*)d_in[15];
  const float* Wh1  = (const float*)d_in[16];
  const float* bh1  = (const float*)d_in[17];
  const float* Who  = (const float*)d_in[18];
  const float* bho  = (const float*)d_in[19];

  float* out_x = (float*)d_out;                 // [512,8,3]
  float* out_h = out_x + N_NODES * NH * 3;      // [512,128]

  // ws layout (float units): mi[131072] | shift[12288] | P[131072] | Q[131072] | wsB(bf16)
  float* ws    = (float*)d_ws;
  float* mi    = ws;
  float* shift = ws + 131072;
  float* P     = ws + 143360;
  float* Q     = ws + 274432;
  unsigned short* wsB = (unsigned short*)(ws + 405504);

  hipMemsetAsync(mi, 0, (131072 + 12288) * sizeof(float), stream);

  k_prep<<<784, 256, 0, stream>>>(We1, Wx0, Wx1, Wxo, wsB);
  k_pq<<<N_NODES, 256, 0, stream>>>(x, h, We0, P, Q);
  k_edge<<<dim3(N_NODES, N_NODES / JTILE), 256, 0, stream>>>(
      x, P, Q, We0, be0, be1, Winf, binf, bx0, bx1, bxo, wsB, mi, shift);
  k_xout<<<(N_NODES * NH * 3 + 255) / 256, 256, 0, stream>>>(x, shift, out_x);
  k_hout<<<N_NODES, 256, 0, stream>>>(h, mi, Wh0, bh0, Wh1, bh1, Who, bho, out_h);
}